// Round 5
// baseline (457.604 us; speedup 1.0000x reference)
//
#include <hip/hip_runtime.h>
#include <hip/hip_bf16.h>

// ---------------- degree ----------------
__global__ __launch_bounds__(256) void k_deg(const int* __restrict__ dst, int* __restrict__ deg, int E) {
    int e = blockIdx.x * 256 + threadIdx.x;
    if (e < E) atomicAdd(&deg[dst[e]], 1);
}

// dinv[n] = rsqrt(deg[n] + 1)   (self-loop)
__global__ __launch_bounds__(256) void k_dinv(const int* __restrict__ deg, float* __restrict__ dinv, int N) {
    int n = blockIdx.x * 256 + threadIdx.x;
    if (n < N) dinv[n] = rsqrtf((float)(deg[n] + 1));
}

// ---------------- CSR build: 3-kernel exclusive scan + atomic-cursor fill ----------------
__global__ __launch_bounds__(256) void k_scan_sum(const int* __restrict__ deg, int* __restrict__ bsum, int N) {
    int n = blockIdx.x * 256 + threadIdx.x;
    int v = (n < N) ? deg[n] : 0;
#pragma unroll
    for (int o = 32; o > 0; o >>= 1) v += __shfl_down(v, o, 64);
    __shared__ int sh[4];
    if ((threadIdx.x & 63) == 0) sh[threadIdx.x >> 6] = v;
    __syncthreads();
    if (threadIdx.x == 0) bsum[blockIdx.x] = sh[0] + sh[1] + sh[2] + sh[3];
}

__global__ __launch_bounds__(256) void k_scan_off(int* __restrict__ bsum, int nb) {
    __shared__ int sh[256];
    int t = threadIdx.x;
    sh[t] = (t < nb) ? bsum[t] : 0;
    __syncthreads();
    for (int o = 1; o < 256; o <<= 1) {
        int y = (t >= o) ? sh[t - o] : 0;
        __syncthreads();
        sh[t] += y;
        __syncthreads();
    }
    if (t < nb) bsum[t] = (t == 0) ? 0 : sh[t - 1];
}

__global__ __launch_bounds__(256) void k_scan_write(const int* __restrict__ deg, const int* __restrict__ boff,
                                                    int* __restrict__ row_start, int* __restrict__ cursor, int N) {
    int n = blockIdx.x * 256 + threadIdx.x;
    int t = threadIdx.x, lane = t & 63, w = t >> 6;
    int v = (n < N) ? deg[n] : 0;
    int x = v;
#pragma unroll
    for (int o = 1; o < 64; o <<= 1) {
        int y = __shfl_up(x, o, 64);
        if (lane >= o) x += y;
    }
    __shared__ int wsum[4];
    if (lane == 63) wsum[w] = x;
    __syncthreads();
    int wo = 0;
#pragma unroll
    for (int i = 0; i < 4; ++i) wo += (i < w) ? wsum[i] : 0;
    int excl = boff[blockIdx.x] + wo + x - v;
    if (n < N) { row_start[n] = excl; cursor[n] = excl; }
    if (n == N - 1) row_start[N] = excl + v;
}

// PAIR: item[pos] = {src[e], e} (int2) ; else item[pos] = e (int)
template <bool PAIR>
__global__ __launch_bounds__(256) void k_fill(const int* __restrict__ src, const int* __restrict__ dst,
                                              int* __restrict__ cursor, void* __restrict__ item, int E) {
    int e = blockIdx.x * 256 + threadIdx.x;
    if (e < E) {
        int d = dst[e];
        int pos = atomicAdd(&cursor[d], 1);
        if (PAIR) ((int2*)item)[pos] = make_int2(src[e], e);
        else      ((int*)item)[pos] = e;
    }
}

// ---------------- dvec[i] = d for CSR position i ----------------
__global__ __launch_bounds__(256) void k_dvec(const int* __restrict__ rowst, int* __restrict__ dvec, int N) {
    int w = threadIdx.x >> 6, lane = threadIdx.x & 63;
    int d = blockIdx.x * 4 + w;
    if (d >= N) return;
    int beg = rowst[d], end = rowst[d + 1];
    for (int k = beg + lane; k < end; k += 64) dvec[k] = d;
}

// ---------------- tiny transpose ----------------
__global__ __launch_bounds__(256) void k_tr(const float* __restrict__ in, float* __restrict__ outp, int R, int C) {
    int i = blockIdx.x * 256 + threadIdx.x;
    if (i < R * C) {
        int r = i / C, c = i % C;
        outp[(size_t)c * R + r] = in[(size_t)r * C + c];
    }
}

// WPQ[j][k]: j<64 -> Wa^T (Wm1[k][j]), else Wb^T (Wm1[64+k][j-64])
__global__ __launch_bounds__(256) void k_wpq(const float* __restrict__ Wm1, float* __restrict__ WPQ) {
    int i = blockIdx.x * 256 + threadIdx.x;
    if (i < 128 * 64) {
        int j = i >> 6, k = i & 63;
        WPQ[i] = (j < 64) ? Wm1[k * 64 + j] : Wm1[(64 + k) * 64 + (j - 64)];
    }
}

// ---------------- column-sliced node GEMM (HW-proven round 2) ----------------
// SCALE: write acc*dinv[n]  ("hs" pre-scaled hidden rows)
template <int K, bool RELU, bool BIAS, bool SCALE>
__global__ __launch_bounds__(256) void k_mm_slice(const float* __restrict__ X,
                                                  const float* __restrict__ WT,   // [64][K]
                                                  const float* __restrict__ bias,
                                                  const float* __restrict__ dinv,
                                                  float* __restrict__ Y, int N) {
    int n = blockIdx.x * 256 + threadIdx.x;
    int j0 = blockIdx.y * 16;
    int nc = n < N ? n : N - 1;
    const float* xr = X + (size_t)nc * K;
    const float* wr = WT + (size_t)j0 * K;
    float acc[16];
#pragma unroll
    for (int j = 0; j < 16; ++j) acc[j] = BIAS ? bias[j0 + j] : 0.f;
#pragma unroll 1
    for (int k0 = 0; k0 < K; k0 += 8) {
        float ef[8];
        *(float4*)(ef)     = *(const float4*)(xr + k0);
        *(float4*)(ef + 4) = *(const float4*)(xr + k0 + 4);
        if (RELU) {
#pragma unroll
            for (int kk = 0; kk < 8; ++kk) ef[kk] = fmaxf(ef[kk], 0.f);
        }
#pragma unroll
        for (int j = 0; j < 16; ++j) {
#pragma unroll
            for (int kk = 0; kk < 8; ++kk)
                acc[j] = fmaf(ef[kk], wr[j * K + k0 + kk], acc[j]);
        }
    }
    if (n < N) {
        if (SCALE) {
            float dn = dinv[n];
#pragma unroll
            for (int j = 0; j < 16; ++j) acc[j] *= dn;
        }
        float4* yp = (float4*)(Y + (size_t)n * 64 + j0);
#pragma unroll
        for (int q = 0; q < 4; ++q) yp[q] = *(float4*)(acc + q * 4);
    }
}

// ---------------- fused P+Q GEMM: gridDim.y=4; thread computes P-slice AND Q-slice (A2 read once) ----------------
__global__ __launch_bounds__(256) void k_pq_slice(const float* __restrict__ A2,
                                                  const float* __restrict__ WPQ,  // [128][64]
                                                  const float* __restrict__ bm1,
                                                  float* __restrict__ Pb, float* __restrict__ Qb, int N) {
    int n = blockIdx.x * 256 + threadIdx.x;
    int jo = blockIdx.y * 16;
    int nc = n < N ? n : N - 1;
    const float* xr = A2 + (size_t)nc * 64;
    const float* wp = WPQ + (size_t)jo * 64;
    const float* wq = WPQ + (size_t)(64 + jo) * 64;
    float ap[16], aq[16];
#pragma unroll
    for (int j = 0; j < 16; ++j) { ap[j] = bm1[jo + j]; aq[j] = 0.f; }
#pragma unroll 1
    for (int k0 = 0; k0 < 64; k0 += 8) {
        float ef[8];
        *(float4*)(ef)     = *(const float4*)(xr + k0);
        *(float4*)(ef + 4) = *(const float4*)(xr + k0 + 4);
#pragma unroll
        for (int kk = 0; kk < 8; ++kk) ef[kk] = fmaxf(ef[kk], 0.f);
#pragma unroll
        for (int j = 0; j < 16; ++j) {
#pragma unroll
            for (int kk = 0; kk < 8; ++kk) {
                ap[j] = fmaf(ef[kk], wp[j * 64 + k0 + kk], ap[j]);
                aq[j] = fmaf(ef[kk], wq[j * 64 + k0 + kk], aq[j]);
            }
        }
    }
    if (n < N) {
        float4* pp = (float4*)(Pb + (size_t)n * 64 + jo);
        float4* qp = (float4*)(Qb + (size_t)n * 64 + jo);
#pragma unroll
        for (int q = 0; q < 4; ++q) {
            pp[q] = *(float4*)(ap + q * 4);
            qp[q] = *(float4*)(aq + q * 4);
        }
    }
}

// ---------------- CSR gather over pre-scaled rows ----------------
template <bool PAIR>
__global__ __launch_bounds__(256) void k_gather(const float* __restrict__ hs, const float* __restrict__ dinv,
                                                const int* __restrict__ row_start, const void* __restrict__ item,
                                                const int* __restrict__ srcArr,
                                                const float* __restrict__ bias,
                                                float* __restrict__ a, int N) {
    int w = threadIdx.x >> 6, lane = threadIdx.x & 63;
    int d = blockIdx.x * 4 + w;
    if (d >= N) return;
    int beg = row_start[d], end = row_start[d + 1];
    float dd = dinv[d];
    float acc = hs[(size_t)d * 64 + lane];   // self-loop term (pre-scaled)
    int k = beg;
    for (; k + 8 <= end; k += 8) {
        int ss[8];
        if (PAIR) {
            const int2* it = (const int2*)item;
#pragma unroll
            for (int u = 0; u < 8; ++u) ss[u] = it[k + u].x;
        } else {
            const int* eid = (const int*)item;
            int ee[8];
#pragma unroll
            for (int u = 0; u < 8; ++u) ee[u] = eid[k + u];
#pragma unroll
            for (int u = 0; u < 8; ++u) ss[u] = srcArr[ee[u]];
        }
        float v[8];
#pragma unroll
        for (int u = 0; u < 8; ++u) v[u] = hs[(size_t)ss[u] * 64 + lane];
#pragma unroll
        for (int u = 0; u < 8; ++u) acc += v[u];
    }
    for (; k < end; ++k) {
        int s = PAIR ? ((const int2*)item)[k].x : srcArr[((const int*)item)[k]];
        acc += hs[(size_t)s * 64 + lane];
    }
    a[(size_t)d * 64 + lane] = fmaf(acc, dd, bias[lane]);
}

// ---------------- fallback P pass (row-local, in-place over A2) ----------------
__global__ __launch_bounds__(256) void k_p_inplace(float* __restrict__ A2P,
                                                   const float* __restrict__ WPQ,
                                                   const float* __restrict__ bm1, int N) {
    int n = blockIdx.x * 256 + threadIdx.x;
    int nc = n < N ? n : N - 1;
    const float* xr = A2P + (size_t)nc * 64;
    float acc[64];
#pragma unroll
    for (int j = 0; j < 64; ++j) acc[j] = bm1[j];
#pragma unroll 1
    for (int k0 = 0; k0 < 64; k0 += 8) {
        float ef[8];
        *(float4*)(ef)     = *(const float4*)(xr + k0);
        *(float4*)(ef + 4) = *(const float4*)(xr + k0 + 4);
#pragma unroll
        for (int kk = 0; kk < 8; ++kk) ef[kk] = fmaxf(ef[kk], 0.f);
#pragma unroll
        for (int j = 0; j < 64; ++j)
#pragma unroll
            for (int kk = 0; kk < 8; ++kk)
                acc[j] = fmaf(ef[kk], WPQ[j * 64 + k0 + kk], acc[j]);
    }
    if (n < N) {
#pragma unroll
        for (int q = 0; q < 16; ++q)
            *(float4*)(A2P + (size_t)n * 64 + q * 4) = *(float4*)(acc + q * 4);
    }
}

// ---------------- edge epilogue, ORIGINAL order (tier-2 fallback) ----------------
__global__ __launch_bounds__(256) void k_edge_pq(const float* __restrict__ P,
                                                 const float* __restrict__ Q,
                                                 const int* __restrict__ src,
                                                 const int* __restrict__ dst,
                                                 const float* __restrict__ W2T,
                                                 const float* __restrict__ bm2,
                                                 float* __restrict__ out, int E) {
    int e = blockIdx.x * 256 + threadIdx.x;
    int ec = e < E ? e : E - 1;
    int s = src[ec], d = dst[ec];
    const float4* p4 = (const float4*)(P + (size_t)s * 64);
    const float4* q4 = (const float4*)(Q + (size_t)d * 64);
    float z[64];
#pragma unroll
    for (int c = 0; c < 16; ++c) {
        float4 a = p4[c], b = q4[c];
        z[c * 4 + 0] = fmaxf(a.x + b.x, 0.f);
        z[c * 4 + 1] = fmaxf(a.y + b.y, 0.f);
        z[c * 4 + 2] = fmaxf(a.z + b.z, 0.f);
        z[c * 4 + 3] = fmaxf(a.w + b.w, 0.f);
    }
    float o[16];
#pragma unroll
    for (int c = 0; c < 16; ++c) {
        float a = bm2[c];
#pragma unroll
        for (int j = 0; j < 64; ++j) a = fmaf(z[j], W2T[c * 64 + j], a);
        o[c] = a;
    }
    if (e < E) {
        float4* op = (float4*)(out + (size_t)e * 16);
#pragma unroll
        for (int q = 0; q < 4; ++q) op[q] = *(float4*)(o + q * 4);
    }
}

// ---------------- edge epilogue, CSR order, LDS-staged P rows ----------------
// Block = 256 consecutive CSR positions. Phase 1: 16 quarter-waves stage the 256
// random P rows into LDS via fully-coalesced 256B bursts (16 lanes x float4),
// chunk-rotated by row for bank-uniform ds traffic. Phase 2: thread = edge,
// P from LDS, Q from global (dst-sorted -> L1 broadcast), out[eid] scattered.
template <bool PAIR>
__global__ __launch_bounds__(256) void k_edge_tile(const float* __restrict__ P,
                                                   const float* __restrict__ Q,
                                                   const int* __restrict__ dvec,
                                                   const void* __restrict__ item,
                                                   const int* __restrict__ srcArr,
                                                   const float* __restrict__ W2T,  // [16][64]
                                                   const float* __restrict__ bm2,
                                                   float* __restrict__ out, int E) {
    __shared__ float ldsP[256 * 64];   // 64 KB
    const int t = threadIdx.x;
    const int base = blockIdx.x * 256;
    const int i = base + t;
    const int ic = i < E ? i : E - 1;
    int e_own;
    if (PAIR) e_own = ((const int2*)item)[ic].y;
    else      e_own = ((const int*)item)[ic];
    const int d = dvec[ic];
    // ---- stage ----
    const int g = t >> 4, c = t & 15;
#pragma unroll 4
    for (int it = 0; it < 16; ++it) {
        int r = it * 16 + g;
        int rc = (base + r) < E ? base + r : E - 1;
        int sr;
        if (PAIR) sr = ((const int2*)item)[rc].x;      // 16 lanes same addr -> broadcast
        else      sr = srcArr[((const int*)item)[rc]];
        float4 v = *(const float4*)(P + (size_t)sr * 64 + c * 4);
        *(float4*)(ldsP + r * 64 + (((c + r) & 15) << 2)) = v;
    }
    __syncthreads();
    // ---- compute ----
    const float4* q4 = (const float4*)(Q + (size_t)d * 64);
    float o[16];
#pragma unroll
    for (int u = 0; u < 16; ++u) o[u] = bm2[u];
#pragma unroll
    for (int cc = 0; cc < 16; ++cc) {
        float4 p = *(const float4*)(ldsP + t * 64 + (((cc + t) & 15) << 2));
        float4 q = q4[cc];
        float z0 = fmaxf(p.x + q.x, 0.f);
        float z1 = fmaxf(p.y + q.y, 0.f);
        float z2 = fmaxf(p.z + q.z, 0.f);
        float z3 = fmaxf(p.w + q.w, 0.f);
#pragma unroll
        for (int u = 0; u < 16; ++u) {
            o[u] = fmaf(z0, W2T[u * 64 + cc * 4 + 0], o[u]);
            o[u] = fmaf(z1, W2T[u * 64 + cc * 4 + 1], o[u]);
            o[u] = fmaf(z2, W2T[u * 64 + cc * 4 + 2], o[u]);
            o[u] = fmaf(z3, W2T[u * 64 + cc * 4 + 3], o[u]);
        }
    }
    if (i < E) {
        float4* op = (float4*)(out + (size_t)e_own * 16);
#pragma unroll
        for (int q = 0; q < 4; ++q) op[q] = *(float4*)(o + q * 4);
    }
}

extern "C" void kernel_launch(void* const* d_in, const int* in_sizes, int n_in,
                              void* d_out, int out_size, void* d_ws, size_t ws_size,
                              hipStream_t stream) {
    const float* x   = (const float*)d_in[0];
    const int* ei    = (const int*)d_in[1];
    const float* W1  = (const float*)d_in[2];
    const float* b1  = (const float*)d_in[3];
    const float* W2  = (const float*)d_in[4];
    const float* b2  = (const float*)d_in[5];
    const float* Wm1 = (const float*)d_in[6];
    const float* bm1 = (const float*)d_in[7];
    const float* Wm2 = (const float*)d_in[8];
    const float* bm2 = (const float*)d_in[9];
    float* out = (float*)d_out;

    const int H  = in_sizes[3];          // 64
    const int IN = in_sizes[2] / H;      // 128
    const int N  = in_sizes[0] / IN;     // 50000
    const int E  = in_sizes[1] / 2;      // 800000
    const int* src = ei;
    const int* dst = ei + E;

    auto al = [](size_t b) { return (b + 255) & ~(size_t)255; };
    char* ws = (char*)d_ws;

    const size_t wb     = al((size_t)IN * H * 4) + al((size_t)H * H * 4) + al((size_t)2 * H * H * 4) + al((size_t)H * 16 * 4);
    const size_t rowstB = al(((size_t)N + 1) * 4);
    const size_t nodeB  = al((size_t)N * 64 * 4);
    const size_t pairB  = al((size_t)E * 8);
    const size_t eidB   = al((size_t)E * 4);
    const size_t needA  = wb + rowstB + pairB + 3 * nodeB;   // ~45.1 MB
    const size_t needB  = wb + rowstB + eidB  + 3 * nodeB;   // ~41.9 MB

    // tier 0: int2{src,eid} CSR epilogue; tier 1: eid-only (src via ei); tier 2: round-2 fallback
    const int tier = (needA <= ws_size) ? 0 : (needB <= ws_size) ? 1 : 2;

    float *W1T, *W2T, *WPQ, *Wm2T, *bufB, *Qbuf, *Pbuf, *dinv;
    int *deg, *rowst, *cursor, *bsum;
    void* item;
    float* bufA = (float*)d_out;   // hs buffer: dead before the epilogue writes out
    bool slicedP = true;

    size_t off = 0;
    auto alc = [&](size_t b) { void* p = ws + off; off += al(b); return p; };

    if (tier <= 1) {
        W1T  = (float*)alc((size_t)IN * H * 4);
        W2T  = (float*)alc((size_t)H * H * 4);
        WPQ  = (float*)alc((size_t)2 * H * H * 4);
        Wm2T = (float*)alc((size_t)H * 16 * 4);
        rowst = (int*)alc(((size_t)N + 1) * 4);
        item  = alc(tier == 0 ? (size_t)E * 8 : (size_t)E * 4);
        bufB = (float*)alc((size_t)N * 64 * 4);
        Qbuf = (float*)alc((size_t)N * 64 * 4);
        Pbuf = (float*)alc((size_t)N * 64 * 4);
        // deg/dinv/cursor/bsum alias Pbuf: all dead before the P/Q GEMM writes Pbuf
        char* pz = (char*)Pbuf;
        dinv   = (float*)pz;
        deg    = (int*)(pz + al((size_t)N * 4));
        cursor = (int*)(pz + 2 * al((size_t)N * 4));
        bsum   = (int*)(pz + 3 * al((size_t)N * 4));
    } else {
        // round-2 proven layout: CSR lives in Qbuf (consumed before Q-GEMM writes it)
        dinv = (float*)alc((size_t)N * 4);
        W1T  = (float*)alc((size_t)IN * H * 4);
        W2T  = (float*)alc((size_t)H * H * 4);
        WPQ  = (float*)alc((size_t)2 * H * H * 4);
        Wm2T = (float*)alc((size_t)H * 16 * 4);
        bufB = (float*)alc((size_t)N * 64 * 4);
        Qbuf = (float*)alc((size_t)N * 64 * 4);
        float* PbufSep = (float*)alc((size_t)N * 64 * 4);
        slicedP = (off <= ws_size);
        Pbuf = slicedP ? PbufSep : bufB;
        char* qz = (char*)Qbuf;
        size_t qo = 0;
        deg    = (int*)(qz + qo); qo += al((size_t)N * 4);
        rowst  = (int*)(qz + qo); qo += al(((size_t)N + 1) * 4);
        cursor = (int*)(qz + qo); qo += al((size_t)N * 4);
        bsum   = (int*)(qz + qo); qo += al(1024);
        item   = (void*)(qz + qo);                      // int2 pairs, ~6.4 MB, fits in 12.8
    }

    const int NBn = (N + 255) / 256;   // 196 (<=256 required by k_scan_off)
    const int NBe = (E + 255) / 256;
    const int NG  = (N + 3) / 4;

    // ---- degree + dinv + CSR build ----
    hipMemsetAsync(deg, 0, (size_t)N * sizeof(int), stream);
    k_deg<<<NBe, 256, 0, stream>>>(dst, deg, E);
    k_dinv<<<NBn, 256, 0, stream>>>(deg, dinv, N);
    k_scan_sum<<<NBn, 256, 0, stream>>>(deg, bsum, N);
    k_scan_off<<<1, 256, 0, stream>>>(bsum, NBn);
    k_scan_write<<<NBn, 256, 0, stream>>>(deg, bsum, rowst, cursor, N);
    if (tier == 1) k_fill<false><<<NBe, 256, 0, stream>>>(src, dst, cursor, item, E);
    else           k_fill<true ><<<NBe, 256, 0, stream>>>(src, dst, cursor, item, E);

    // ---- weight transposes ----
    k_tr<<<(IN * H + 255) / 256, 256, 0, stream>>>(W1, W1T, IN, H);
    k_tr<<<(H * H + 255) / 256, 256, 0, stream>>>(W2, W2T, H, H);
    k_tr<<<(H * 16 + 255) / 256, 256, 0, stream>>>(Wm2, Wm2T, H, 16);
    k_wpq<<<(2 * H * H + 255) / 256, 256, 0, stream>>>(Wm1, WPQ);

    const dim3 G4(NBn, 4);

    // layer 1: hs1 = (x@W1)*dinv -> bufA ; a1 = b1 + dd*(hs1[d] + sum hs1[s]) -> bufB
    k_mm_slice<128, false, false, true><<<G4, 256, 0, stream>>>(x, W1T, nullptr, dinv, bufA, N);
    if (tier == 1) k_gather<false><<<NG, 256, 0, stream>>>(bufA, dinv, rowst, item, src, b1, bufB, N);
    else           k_gather<true ><<<NG, 256, 0, stream>>>(bufA, dinv, rowst, item, src, b1, bufB, N);

    // layer 2: hs2 = (relu(a1)@W2)*dinv -> bufA ; a2 -> bufB
    k_mm_slice<64, true, false, true><<<G4, 256, 0, stream>>>(bufB, W2T, nullptr, dinv, bufA, N);
    if (tier == 1) k_gather<false><<<NG, 256, 0, stream>>>(bufA, dinv, rowst, item, src, b2, bufB, N);
    else           k_gather<true ><<<NG, 256, 0, stream>>>(bufA, dinv, rowst, item, src, b2, bufB, N);

    // node-side MLP halves
    if (tier <= 1) {
        // fused P+Q in one dispatch, A2 read once per y-slice (dinv dead from here)
        k_pq_slice<<<G4, 256, 0, stream>>>(bufB, WPQ, bm1, Pbuf, Qbuf, N);
        // dvec into bufB (a2 dead after k_pq_slice)
        int* dvec = (int*)bufB;
        k_dvec<<<NG, 256, 0, stream>>>(rowst, dvec, N);
        if (tier == 0) k_edge_tile<true ><<<NBe, 256, 0, stream>>>(Pbuf, Qbuf, dvec, item, src, Wm2T, bm2, out, E);
        else           k_edge_tile<false><<<NBe, 256, 0, stream>>>(Pbuf, Qbuf, dvec, item, src, Wm2T, bm2, out, E);
    } else {
        k_mm_slice<64, true, false, false><<<G4, 256, 0, stream>>>(bufB, WPQ + 64 * 64, nullptr, nullptr, Qbuf, N);
        if (slicedP) k_mm_slice<64, true, true, false><<<G4, 256, 0, stream>>>(bufB, WPQ, bm1, nullptr, Pbuf, N);
        else         k_p_inplace<<<NBn, 256, 0, stream>>>(bufB, WPQ, bm1, N);
        k_edge_pq<<<NBe, 256, 0, stream>>>(Pbuf, Qbuf, src, dst, Wm2T, bm2, out, E);
    }
}

// Round 7
// 448.824 us; speedup vs baseline: 1.0196x; 1.0196x over previous
//
#include <hip/hip_runtime.h>
#include <hip/hip_bf16.h>

// ---------------- degree ----------------
__global__ __launch_bounds__(256) void k_deg(const int* __restrict__ dst, int* __restrict__ deg, int E) {
    int e = blockIdx.x * 256 + threadIdx.x;
    if (e < E) atomicAdd(&deg[dst[e]], 1);
}

// ---------------- CSR build: scan_sum (+fused dinv) + scan_off + scan_write + fill ----------------
__global__ __launch_bounds__(256) void k_scan_sum(const int* __restrict__ deg, int* __restrict__ bsum,
                                                  float* __restrict__ dinv, int N) {
    int n = blockIdx.x * 256 + threadIdx.x;
    int v = (n < N) ? deg[n] : 0;
    if (n < N) dinv[n] = rsqrtf((float)(v + 1));   // fused: dinv = rsqrt(deg+1) (self-loop)
    int r = v;
#pragma unroll
    for (int o = 32; o > 0; o >>= 1) r += __shfl_down(r, o, 64);
    __shared__ int sh[4];
    if ((threadIdx.x & 63) == 0) sh[threadIdx.x >> 6] = r;
    __syncthreads();
    if (threadIdx.x == 0) bsum[blockIdx.x] = sh[0] + sh[1] + sh[2] + sh[3];
}

__global__ __launch_bounds__(256) void k_scan_off(int* __restrict__ bsum, int nb) {
    __shared__ int sh[256];
    int t = threadIdx.x;
    sh[t] = (t < nb) ? bsum[t] : 0;
    __syncthreads();
    for (int o = 1; o < 256; o <<= 1) {
        int y = (t >= o) ? sh[t - o] : 0;
        __syncthreads();
        sh[t] += y;
        __syncthreads();
    }
    if (t < nb) bsum[t] = (t == 0) ? 0 : sh[t - 1];
}

__global__ __launch_bounds__(256) void k_scan_write(const int* __restrict__ deg, const int* __restrict__ boff,
                                                    int* __restrict__ row_start, int* __restrict__ cursor, int N) {
    int n = blockIdx.x * 256 + threadIdx.x;
    int t = threadIdx.x, lane = t & 63, w = t >> 6;
    int v = (n < N) ? deg[n] : 0;
    int x = v;
#pragma unroll
    for (int o = 1; o < 64; o <<= 1) {
        int y = __shfl_up(x, o, 64);
        if (lane >= o) x += y;
    }
    __shared__ int wsum[4];
    if (lane == 63) wsum[w] = x;
    __syncthreads();
    int wo = 0;
#pragma unroll
    for (int i = 0; i < 4; ++i) wo += (i < w) ? wsum[i] : 0;
    int excl = boff[blockIdx.x] + wo + x - v;
    if (n < N) { row_start[n] = excl; cursor[n] = excl; }
    if (n == N - 1) row_start[N] = excl + v;
}

// PAIR: item[pos] = {src[e], e} (int2) ; else item[pos] = e (int)
template <bool PAIR>
__global__ __launch_bounds__(256) void k_fill(const int* __restrict__ src, const int* __restrict__ dst,
                                              int* __restrict__ cursor, void* __restrict__ item, int E) {
    int e = blockIdx.x * 256 + threadIdx.x;
    if (e < E) {
        int d = dst[e];
        int pos = atomicAdd(&cursor[d], 1);
        if (PAIR) ((int2*)item)[pos] = make_int2(src[e], e);
        else      ((int*)item)[pos] = e;
    }
}

// ---------------- dvec[i] = d for CSR position i ----------------
__global__ __launch_bounds__(256) void k_dvec(const int* __restrict__ rowst, int* __restrict__ dvec, int N) {
    int w = threadIdx.x >> 6, lane = threadIdx.x & 63;
    int d = blockIdx.x * 4 + w;
    if (d >= N) return;
    int beg = rowst[d], end = rowst[d + 1];
    for (int k = beg + lane; k < end; k += 64) dvec[k] = d;
}

// ---------------- merged weight prep: W1T, W2T, Wm2T, WPQ in one dispatch ----------------
__global__ __launch_bounds__(256) void k_prep(const float* __restrict__ W1, const float* __restrict__ W2,
                                              const float* __restrict__ Wm2, const float* __restrict__ Wm1,
                                              float* __restrict__ W1T, float* __restrict__ W2T,
                                              float* __restrict__ Wm2T, float* __restrict__ WPQ,
                                              int IN, int H) {
    int i = blockIdx.x * 256 + threadIdx.x;
    int n1 = IN * H, n2 = H * H, n3 = H * 16, n4 = 2 * H * H;
    if (i < n1) {
        int r = i / H, c = i % H;
        W1T[(size_t)c * IN + r] = W1[(size_t)r * H + c];
    } else if ((i -= n1) < n2) {
        int r = i / H, c = i % H;
        W2T[(size_t)c * H + r] = W2[(size_t)r * H + c];
    } else if ((i -= n2) < n3) {
        int r = i / 16, c = i % 16;
        Wm2T[(size_t)c * H + r] = Wm2[(size_t)r * 16 + c];
    } else if ((i -= n3) < n4) {
        int j = i >> 6, k = i & 63;   // H == 64
        WPQ[i] = (j < 64) ? Wm1[k * 64 + j] : Wm1[(64 + k) * 64 + (j - 64)];
    }
}

// ---------------- column-sliced node GEMM (HW-proven round 2) ----------------
// SCALE: write acc*dinv[n]  ("hs" pre-scaled hidden rows)
template <int K, bool RELU, bool BIAS, bool SCALE>
__global__ __launch_bounds__(256) void k_mm_slice(const float* __restrict__ X,
                                                  const float* __restrict__ WT,   // [64][K]
                                                  const float* __restrict__ bias,
                                                  const float* __restrict__ dinv,
                                                  float* __restrict__ Y, int N) {
    int n = blockIdx.x * 256 + threadIdx.x;
    int j0 = blockIdx.y * 16;
    int nc = n < N ? n : N - 1;
    const float* xr = X + (size_t)nc * K;
    const float* wr = WT + (size_t)j0 * K;
    float acc[16];
#pragma unroll
    for (int j = 0; j < 16; ++j) acc[j] = BIAS ? bias[j0 + j] : 0.f;
#pragma unroll 1
    for (int k0 = 0; k0 < K; k0 += 8) {
        float ef[8];
        *(float4*)(ef)     = *(const float4*)(xr + k0);
        *(float4*)(ef + 4) = *(const float4*)(xr + k0 + 4);
        if (RELU) {
#pragma unroll
            for (int kk = 0; kk < 8; ++kk) ef[kk] = fmaxf(ef[kk], 0.f);
        }
#pragma unroll
        for (int j = 0; j < 16; ++j) {
#pragma unroll
            for (int kk = 0; kk < 8; ++kk)
                acc[j] = fmaf(ef[kk], wr[j * K + k0 + kk], acc[j]);
        }
    }
    if (n < N) {
        if (SCALE) {
            float dn = dinv[n];
#pragma unroll
            for (int j = 0; j < 16; ++j) acc[j] *= dn;
        }
        float4* yp = (float4*)(Y + (size_t)n * 64 + j0);
#pragma unroll
        for (int q = 0; q < 4; ++q) yp[q] = *(float4*)(acc + q * 4);
    }
}

// ---------------- fused P+Q GEMM (round-4 proven G8 form): y<4 -> P(+bm1), y>=4 -> Q ----------------
__global__ __launch_bounds__(256) void k_pq_slice(const float* __restrict__ A2,
                                                  const float* __restrict__ WPQ,  // [128][64]
                                                  const float* __restrict__ bm1,
                                                  float* __restrict__ Pb, float* __restrict__ Qb, int N) {
    int n = blockIdx.x * 256 + threadIdx.x;
    int j0g = blockIdx.y * 16;           // 0..127 row into WPQ
    bool isP = j0g < 64;
    int jo = isP ? j0g : j0g - 64;
    float* Y = isP ? Pb : Qb;
    int nc = n < N ? n : N - 1;
    const float* xr = A2 + (size_t)nc * 64;
    const float* wr = WPQ + (size_t)j0g * 64;
    float acc[16];
#pragma unroll
    for (int j = 0; j < 16; ++j) acc[j] = isP ? bm1[jo + j] : 0.f;
#pragma unroll 1
    for (int k0 = 0; k0 < 64; k0 += 8) {
        float ef[8];
        *(float4*)(ef)     = *(const float4*)(xr + k0);
        *(float4*)(ef + 4) = *(const float4*)(xr + k0 + 4);
#pragma unroll
        for (int kk = 0; kk < 8; ++kk) ef[kk] = fmaxf(ef[kk], 0.f);
#pragma unroll
        for (int j = 0; j < 16; ++j)
#pragma unroll
            for (int kk = 0; kk < 8; ++kk)
                acc[j] = fmaf(ef[kk], wr[j * 64 + k0 + kk], acc[j]);
    }
    if (n < N) {
        float4* yp = (float4*)(Y + (size_t)n * 64 + jo);
#pragma unroll
        for (int q = 0; q < 4; ++q) yp[q] = *(float4*)(acc + q * 4);
    }
}

// ---------------- CSR gather over pre-scaled rows: a[d] = bias + dd*(hs[d] + sum_e hs[src_e]) ----------------
// wave = dst node, lane = column. 16-row, then 8-row batches in flight.
template <bool PAIR>
__global__ __launch_bounds__(256) void k_gather(const float* __restrict__ hs, const float* __restrict__ dinv,
                                                const int* __restrict__ row_start, const void* __restrict__ item,
                                                const int* __restrict__ srcArr,
                                                const float* __restrict__ bias,
                                                float* __restrict__ a, int N) {
    int w = threadIdx.x >> 6, lane = threadIdx.x & 63;
    int d = blockIdx.x * 4 + w;
    if (d >= N) return;
    int beg = row_start[d], end = row_start[d + 1];
    float dd = dinv[d];
    float acc = hs[(size_t)d * 64 + lane];   // self-loop term (pre-scaled)
    int k = beg;
    for (; k + 16 <= end; k += 16) {
        int ss[16];
        if (PAIR) {
            const int2* it = (const int2*)item;
#pragma unroll
            for (int u = 0; u < 16; ++u) ss[u] = it[k + u].x;
        } else {
            const int* eid = (const int*)item;
            int ee[16];
#pragma unroll
            for (int u = 0; u < 16; ++u) ee[u] = eid[k + u];
#pragma unroll
            for (int u = 0; u < 16; ++u) ss[u] = srcArr[ee[u]];
        }
        float v[16];
#pragma unroll
        for (int u = 0; u < 16; ++u) v[u] = hs[(size_t)ss[u] * 64 + lane];
#pragma unroll
        for (int u = 0; u < 16; ++u) acc += v[u];
    }
    for (; k + 8 <= end; k += 8) {
        int ss[8];
        if (PAIR) {
            const int2* it = (const int2*)item;
#pragma unroll
            for (int u = 0; u < 8; ++u) ss[u] = it[k + u].x;
        } else {
            const int* eid = (const int*)item;
            int ee[8];
#pragma unroll
            for (int u = 0; u < 8; ++u) ee[u] = eid[k + u];
#pragma unroll
            for (int u = 0; u < 8; ++u) ss[u] = srcArr[ee[u]];
        }
        float v[8];
#pragma unroll
        for (int u = 0; u < 8; ++u) v[u] = hs[(size_t)ss[u] * 64 + lane];
#pragma unroll
        for (int u = 0; u < 8; ++u) acc += v[u];
    }
    for (; k < end; ++k) {
        int s = PAIR ? ((const int2*)item)[k].x : srcArr[((const int*)item)[k]];
        acc += hs[(size_t)s * 64 + lane];
    }
    a[(size_t)d * 64 + lane] = fmaf(acc, dd, bias[lane]);
}

// ---------------- fallback P pass (row-local, in-place over A2) ----------------
__global__ __launch_bounds__(256) void k_p_inplace(float* __restrict__ A2P,
                                                   const float* __restrict__ WPQ,
                                                   const float* __restrict__ bm1, int N) {
    int n = blockIdx.x * 256 + threadIdx.x;
    int nc = n < N ? n : N - 1;
    const float* xr = A2P + (size_t)nc * 64;
    float acc[64];
#pragma unroll
    for (int j = 0; j < 64; ++j) acc[j] = bm1[j];
#pragma unroll 1
    for (int k0 = 0; k0 < 64; k0 += 8) {
        float ef[8];
        *(float4*)(ef)     = *(const float4*)(xr + k0);
        *(float4*)(ef + 4) = *(const float4*)(xr + k0 + 4);
#pragma unroll
        for (int kk = 0; kk < 8; ++kk) ef[kk] = fmaxf(ef[kk], 0.f);
#pragma unroll
        for (int j = 0; j < 64; ++j)
#pragma unroll
            for (int kk = 0; kk < 8; ++kk)
                acc[j] = fmaf(ef[kk], WPQ[j * 64 + k0 + kk], acc[j]);
    }
    if (n < N) {
#pragma unroll
        for (int q = 0; q < 16; ++q)
            *(float4*)(A2P + (size_t)n * 64 + q * 4) = *(float4*)(acc + q * 4);
    }
}

// ---------------- edge epilogue, ORIGINAL order (tier-2 fallback) ----------------
__global__ __launch_bounds__(256) void k_edge_pq(const float* __restrict__ P,
                                                 const float* __restrict__ Q,
                                                 const int* __restrict__ src,
                                                 const int* __restrict__ dst,
                                                 const float* __restrict__ W2T,
                                                 const float* __restrict__ bm2,
                                                 float* __restrict__ out, int E) {
    int e = blockIdx.x * 256 + threadIdx.x;
    int ec = e < E ? e : E - 1;
    int s = src[ec], d = dst[ec];
    const float4* p4 = (const float4*)(P + (size_t)s * 64);
    const float4* q4 = (const float4*)(Q + (size_t)d * 64);
    float z[64];
#pragma unroll
    for (int c = 0; c < 16; ++c) {
        float4 a = p4[c], b = q4[c];
        z[c * 4 + 0] = fmaxf(a.x + b.x, 0.f);
        z[c * 4 + 1] = fmaxf(a.y + b.y, 0.f);
        z[c * 4 + 2] = fmaxf(a.z + b.z, 0.f);
        z[c * 4 + 3] = fmaxf(a.w + b.w, 0.f);
    }
    float o[16];
#pragma unroll
    for (int c = 0; c < 16; ++c) {
        float a = bm2[c];
#pragma unroll
        for (int j = 0; j < 64; ++j) a = fmaf(z[j], W2T[c * 64 + j], a);
        o[c] = a;
    }
    if (e < E) {
        float4* op = (float4*)(out + (size_t)e * 16);
#pragma unroll
        for (int q = 0; q < 4; ++q) op[q] = *(float4*)(o + q * 4);
    }
}

// ---------------- edge epilogue, CSR order, 2 positions/thread ----------------
// Thread = 2 consecutive CSR positions: one int4/int2 index load, W2T scalar reads
// amortized over both edges, 32 independent P/Q float4 loads in flight per thread.
// Consecutive positions usually share d -> Q row L1-resident.
template <bool PAIR>
__global__ __launch_bounds__(256) void k_edge_csr2(const float* __restrict__ P,
                                                   const float* __restrict__ Q,
                                                   const int* __restrict__ dvec,
                                                   const void* __restrict__ item,
                                                   const int* __restrict__ srcArr,
                                                   const float* __restrict__ W2T,  // [16][64]
                                                   const float* __restrict__ bm2,
                                                   float* __restrict__ out, int E) {
    int i0 = (blockIdx.x * 256 + threadIdx.x) * 2;
    if (i0 >= E) return;
    int i1 = i0 + 1;
    bool has2 = i1 < E;
    int s0, e0, s1, e1;
    if (PAIR) {
        if (has2) {
            int4 pe = ((const int4*)item)[i0 >> 1];   // two int2s, 16B aligned (i0 even)
            s0 = pe.x; e0 = pe.y; s1 = pe.z; e1 = pe.w;
        } else {
            int2 pe = ((const int2*)item)[i0];
            s0 = pe.x; e0 = pe.y; s1 = s0; e1 = e0;
        }
    } else {
        const int* eid = (const int*)item;
        e0 = eid[i0];
        e1 = has2 ? eid[i1] : e0;
        s0 = srcArr[e0];
        s1 = srcArr[e1];
    }
    int d0, d1;
    if (has2) { int2 dd = ((const int2*)dvec)[i0 >> 1]; d0 = dd.x; d1 = dd.y; }
    else      { d0 = dvec[i0]; d1 = d0; }

    const float4* p40 = (const float4*)(P + (size_t)s0 * 64);
    const float4* p41 = (const float4*)(P + (size_t)s1 * 64);
    const float4* q40 = (const float4*)(Q + (size_t)d0 * 64);
    const float4* q41 = (const float4*)(Q + (size_t)d1 * 64);
    float o0[16], o1[16];
#pragma unroll
    for (int u = 0; u < 16; ++u) { float b = bm2[u]; o0[u] = b; o1[u] = b; }
#pragma unroll
    for (int cc = 0; cc < 16; ++cc) {
        float4 a0 = p40[cc], b0 = q40[cc];
        float4 a1 = p41[cc], b1 = q41[cc];
        float z00 = fmaxf(a0.x + b0.x, 0.f), z01 = fmaxf(a0.y + b0.y, 0.f);
        float z02 = fmaxf(a0.z + b0.z, 0.f), z03 = fmaxf(a0.w + b0.w, 0.f);
        float z10 = fmaxf(a1.x + b1.x, 0.f), z11 = fmaxf(a1.y + b1.y, 0.f);
        float z12 = fmaxf(a1.z + b1.z, 0.f), z13 = fmaxf(a1.w + b1.w, 0.f);
#pragma unroll
        for (int u = 0; u < 16; ++u) {
            float w0 = W2T[u * 64 + cc * 4 + 0];
            float w1 = W2T[u * 64 + cc * 4 + 1];
            float w2 = W2T[u * 64 + cc * 4 + 2];
            float w3 = W2T[u * 64 + cc * 4 + 3];
            o0[u] = fmaf(z00, w0, o0[u]); o1[u] = fmaf(z10, w0, o1[u]);
            o0[u] = fmaf(z01, w1, o0[u]); o1[u] = fmaf(z11, w1, o1[u]);
            o0[u] = fmaf(z02, w2, o0[u]); o1[u] = fmaf(z12, w2, o1[u]);
            o0[u] = fmaf(z03, w3, o0[u]); o1[u] = fmaf(z13, w3, o1[u]);
        }
    }
    {
        float4* op = (float4*)(out + (size_t)e0 * 16);
#pragma unroll
        for (int q = 0; q < 4; ++q) op[q] = *(float4*)(o0 + q * 4);
    }
    if (has2) {
        float4* op = (float4*)(out + (size_t)e1 * 16);
#pragma unroll
        for (int q = 0; q < 4; ++q) op[q] = *(float4*)(o1 + q * 4);
    }
}

extern "C" void kernel_launch(void* const* d_in, const int* in_sizes, int n_in,
                              void* d_out, int out_size, void* d_ws, size_t ws_size,
                              hipStream_t stream) {
    const float* x   = (const float*)d_in[0];
    const int* ei    = (const int*)d_in[1];
    const float* W1  = (const float*)d_in[2];
    const float* b1  = (const float*)d_in[3];
    const float* W2  = (const float*)d_in[4];
    const float* b2  = (const float*)d_in[5];
    const float* Wm1 = (const float*)d_in[6];
    const float* bm1 = (const float*)d_in[7];
    const float* Wm2 = (const float*)d_in[8];
    const float* bm2 = (const float*)d_in[9];
    float* out = (float*)d_out;

    const int H  = in_sizes[3];          // 64
    const int IN = in_sizes[2] / H;      // 128
    const int N  = in_sizes[0] / IN;     // 50000
    const int E  = in_sizes[1] / 2;      // 800000
    const int* src = ei;
    const int* dst = ei + E;

    auto al = [](size_t b) { return (b + 255) & ~(size_t)255; };
    char* ws = (char*)d_ws;

    const size_t wb     = al((size_t)IN * H * 4) + al((size_t)H * H * 4) + al((size_t)2 * H * H * 4) + al((size_t)H * 16 * 4);
    const size_t rowstB = al(((size_t)N + 1) * 4);
    const size_t nodeB  = al((size_t)N * 64 * 4);
    const size_t pairB  = al((size_t)E * 8);
    const size_t eidB   = al((size_t)E * 4);
    const size_t needA  = wb + rowstB + pairB + 3 * nodeB;   // ~45.1 MB
    const size_t needB  = wb + rowstB + eidB  + 3 * nodeB;   // ~41.9 MB

    // tier 0: int2{src,eid} CSR epilogue; tier 1: eid-only (src via ei); tier 2: round-2 fallback
    const int tier = (needA <= ws_size) ? 0 : (needB <= ws_size) ? 1 : 2;

    float *W1T, *W2T, *WPQ, *Wm2T, *bufB, *Qbuf, *Pbuf, *dinv;
    int *deg, *rowst, *cursor, *bsum;
    void* item;
    float* bufA = (float*)d_out;   // hs buffer: dead before the epilogue writes out
    bool slicedP = true;

    size_t off = 0;
    auto alc = [&](size_t b) { void* p = ws + off; off += al(b); return p; };

    if (tier <= 1) {
        W1T  = (float*)alc((size_t)IN * H * 4);
        W2T  = (float*)alc((size_t)H * H * 4);
        WPQ  = (float*)alc((size_t)2 * H * H * 4);
        Wm2T = (float*)alc((size_t)H * 16 * 4);
        rowst = (int*)alc(((size_t)N + 1) * 4);
        item  = alc(tier == 0 ? (size_t)E * 8 : (size_t)E * 4);
        bufB = (float*)alc((size_t)N * 64 * 4);
        Qbuf = (float*)alc((size_t)N * 64 * 4);
        Pbuf = (float*)alc((size_t)N * 64 * 4);
        // deg/dinv/cursor/bsum alias Pbuf: all dead before the P/Q GEMM writes Pbuf
        // (dinv last used by the layer-2 GEMM SCALE, which precedes k_pq_slice)
        char* pz = (char*)Pbuf;
        dinv   = (float*)pz;
        deg    = (int*)(pz + al((size_t)N * 4));
        cursor = (int*)(pz + 2 * al((size_t)N * 4));
        bsum   = (int*)(pz + 3 * al((size_t)N * 4));
    } else {
        // round-2 proven layout: CSR lives in Qbuf (consumed before Q-GEMM writes it)
        dinv = (float*)alc((size_t)N * 4);
        W1T  = (float*)alc((size_t)IN * H * 4);
        W2T  = (float*)alc((size_t)H * H * 4);
        WPQ  = (float*)alc((size_t)2 * H * H * 4);
        Wm2T = (float*)alc((size_t)H * 16 * 4);
        bufB = (float*)alc((size_t)N * 64 * 4);
        Qbuf = (float*)alc((size_t)N * 64 * 4);
        float* PbufSep = (float*)alc((size_t)N * 64 * 4);
        slicedP = (off <= ws_size);
        Pbuf = slicedP ? PbufSep : bufB;
        char* qz = (char*)Qbuf;
        size_t qo = 0;
        deg    = (int*)(qz + qo); qo += al((size_t)N * 4);
        rowst  = (int*)(qz + qo); qo += al(((size_t)N + 1) * 4);
        cursor = (int*)(qz + qo); qo += al((size_t)N * 4);
        bsum   = (int*)(qz + qo); qo += al(1024);
        item   = (void*)(qz + qo);                      // int2 pairs, ~6.4 MB, fits in 12.8
    }

    const int NBn = (N + 255) / 256;   // 196 (<=256 required by k_scan_off)
    const int NBe = (E + 255) / 256;
    const int NG  = (N + 3) / 4;
    const int NE2 = ((E + 1) / 2 + 255) / 256;   // edge kernel: 2 CSR positions/thread

    // ---- degree + dinv + CSR build ----
    hipMemsetAsync(deg, 0, (size_t)N * sizeof(int), stream);
    k_deg<<<NBe, 256, 0, stream>>>(dst, deg, E);
    k_scan_sum<<<NBn, 256, 0, stream>>>(deg, bsum, dinv, N);
    k_scan_off<<<1, 256, 0, stream>>>(bsum, NBn);
    k_scan_write<<<NBn, 256, 0, stream>>>(deg, bsum, rowst, cursor, N);
    if (tier == 1) k_fill<false><<<NBe, 256, 0, stream>>>(src, dst, cursor, item, E);
    else           k_fill<true ><<<NBe, 256, 0, stream>>>(src, dst, cursor, item, E);

    // ---- merged weight prep ----
    const int prepElems = IN * H + H * H + H * 16 + 2 * H * H;
    k_prep<<<(prepElems + 255) / 256, 256, 0, stream>>>(W1, W2, Wm2, Wm1, W1T, W2T, Wm2T, WPQ, IN, H);

    const dim3 G4(NBn, 4);
    const dim3 G8(NBn, 8);

    // layer 1: hs1 = (x@W1)*dinv -> bufA ; a1 = b1 + dd*(hs1[d] + sum hs1[s]) -> bufB
    k_mm_slice<128, false, false, true><<<G4, 256, 0, stream>>>(x, W1T, nullptr, dinv, bufA, N);
    if (tier == 1) k_gather<false><<<NG, 256, 0, stream>>>(bufA, dinv, rowst, item, src, b1, bufB, N);
    else           k_gather<true ><<<NG, 256, 0, stream>>>(bufA, dinv, rowst, item, src, b1, bufB, N);

    // layer 2: hs2 = (relu(a1)@W2)*dinv -> bufA ; a2 -> bufB
    k_mm_slice<64, true, false, true><<<G4, 256, 0, stream>>>(bufB, W2T, nullptr, dinv, bufA, N);
    if (tier == 1) k_gather<false><<<NG, 256, 0, stream>>>(bufA, dinv, rowst, item, src, b2, bufB, N);
    else           k_gather<true ><<<NG, 256, 0, stream>>>(bufA, dinv, rowst, item, src, b2, bufB, N);

    // node-side MLP halves
    if (tier <= 1) {
        // fused P+Q dispatch (round-4 proven G8 form); dinv dead from here
        k_pq_slice<<<G8, 256, 0, stream>>>(bufB, WPQ, bm1, Pbuf, Qbuf, N);
        // dvec into bufB (a2 dead after k_pq_slice)
        int* dvec = (int*)bufB;
        k_dvec<<<NG, 256, 0, stream>>>(rowst, dvec, N);
        if (tier == 0) k_edge_csr2<true ><<<NE2, 256, 0, stream>>>(Pbuf, Qbuf, dvec, item, src, Wm2T, bm2, out, E);
        else           k_edge_csr2<false><<<NE2, 256, 0, stream>>>(Pbuf, Qbuf, dvec, item, src, Wm2T, bm2, out, E);
    } else {
        k_mm_slice<64, true, false, false><<<G4, 256, 0, stream>>>(bufB, WPQ + 64 * 64, nullptr, nullptr, Qbuf, N);
        if (slicedP) k_mm_slice<64, true, true, false><<<G4, 256, 0, stream>>>(bufB, WPQ, bm1, nullptr, Pbuf, N);
        else         k_p_inplace<<<NBn, 256, 0, stream>>>(bufB, WPQ, bm1, N);
        k_edge_pq<<<NBe, 256, 0, stream>>>(Pbuf, Qbuf, src, dst, Wm2T, bm2, out, E);
    }
}

// Round 9
// 416.122 us; speedup vs baseline: 1.0997x; 1.0786x over previous
//
#include <hip/hip_runtime.h>
#include <hip/hip_bf16.h>

// ---------------- degree ----------------
__global__ __launch_bounds__(256) void k_deg(const int* __restrict__ dst, int* __restrict__ deg, int E) {
    int e = blockIdx.x * 256 + threadIdx.x;
    if (e < E) atomicAdd(&deg[dst[e]], 1);
}

// ---------------- CSR build: scan_sum (+fused dinv) + scan_off + scan_write + fill ----------------
__global__ __launch_bounds__(256) void k_scan_sum(const int* __restrict__ deg, int* __restrict__ bsum,
                                                  float* __restrict__ dinv, int N) {
    int n = blockIdx.x * 256 + threadIdx.x;
    int v = (n < N) ? deg[n] : 0;
    if (n < N) dinv[n] = rsqrtf((float)(v + 1));   // fused: dinv = rsqrt(deg+1) (self-loop)
    int r = v;
#pragma unroll
    for (int o = 32; o > 0; o >>= 1) r += __shfl_down(r, o, 64);
    __shared__ int sh[4];
    if ((threadIdx.x & 63) == 0) sh[threadIdx.x >> 6] = r;
    __syncthreads();
    if (threadIdx.x == 0) bsum[blockIdx.x] = sh[0] + sh[1] + sh[2] + sh[3];
}

__global__ __launch_bounds__(256) void k_scan_off(int* __restrict__ bsum, int nb) {
    __shared__ int sh[256];
    int t = threadIdx.x;
    sh[t] = (t < nb) ? bsum[t] : 0;
    __syncthreads();
    for (int o = 1; o < 256; o <<= 1) {
        int y = (t >= o) ? sh[t - o] : 0;
        __syncthreads();
        sh[t] += y;
        __syncthreads();
    }
    if (t < nb) bsum[t] = (t == 0) ? 0 : sh[t - 1];
}

__global__ __launch_bounds__(256) void k_scan_write(const int* __restrict__ deg, const int* __restrict__ boff,
                                                    int* __restrict__ row_start, int* __restrict__ cursor, int N) {
    int n = blockIdx.x * 256 + threadIdx.x;
    int t = threadIdx.x, lane = t & 63, w = t >> 6;
    int v = (n < N) ? deg[n] : 0;
    int x = v;
#pragma unroll
    for (int o = 1; o < 64; o <<= 1) {
        int y = __shfl_up(x, o, 64);
        if (lane >= o) x += y;
    }
    __shared__ int wsum[4];
    if (lane == 63) wsum[w] = x;
    __syncthreads();
    int wo = 0;
#pragma unroll
    for (int i = 0; i < 4; ++i) wo += (i < w) ? wsum[i] : 0;
    int excl = boff[blockIdx.x] + wo + x - v;
    if (n < N) { row_start[n] = excl; cursor[n] = excl; }
    if (n == N - 1) row_start[N] = excl + v;
}

// PAIR: item[pos] = {src[e], e} (int2) ; else item[pos] = e (int)
template <bool PAIR>
__global__ __launch_bounds__(256) void k_fill(const int* __restrict__ src, const int* __restrict__ dst,
                                              int* __restrict__ cursor, void* __restrict__ item, int E) {
    int e = blockIdx.x * 256 + threadIdx.x;
    if (e < E) {
        int d = dst[e];
        int pos = atomicAdd(&cursor[d], 1);
        if (PAIR) ((int2*)item)[pos] = make_int2(src[e], e);
        else      ((int*)item)[pos] = e;
    }
}

// ---------------- dvec[i] = d for CSR position i ----------------
__global__ __launch_bounds__(256) void k_dvec(const int* __restrict__ rowst, int* __restrict__ dvec, int N) {
    int w = threadIdx.x >> 6, lane = threadIdx.x & 63;
    int d = blockIdx.x * 4 + w;
    if (d >= N) return;
    int beg = rowst[d], end = rowst[d + 1];
    for (int k = beg + lane; k < end; k += 64) dvec[k] = d;
}

// ---------------- merged weight prep: W1T, W2T, Wm2T, WPQ in one dispatch ----------------
__global__ __launch_bounds__(256) void k_prep(const float* __restrict__ W1, const float* __restrict__ W2,
                                              const float* __restrict__ Wm2, const float* __restrict__ Wm1,
                                              float* __restrict__ W1T, float* __restrict__ W2T,
                                              float* __restrict__ Wm2T, float* __restrict__ WPQ,
                                              int IN, int H) {
    int i = blockIdx.x * 256 + threadIdx.x;
    int n1 = IN * H, n2 = H * H, n3 = H * 16, n4 = 2 * H * H;
    if (i < n1) {
        int r = i / H, c = i % H;
        W1T[(size_t)c * IN + r] = W1[(size_t)r * H + c];
    } else if ((i -= n1) < n2) {
        int r = i / H, c = i % H;
        W2T[(size_t)c * H + r] = W2[(size_t)r * H + c];
    } else if ((i -= n2) < n3) {
        int r = i / 16, c = i % 16;
        Wm2T[(size_t)c * H + r] = Wm2[(size_t)r * 16 + c];
    } else if ((i -= n3) < n4) {
        int j = i >> 6, k = i & 63;   // H == 64
        WPQ[i] = (j < 64) ? Wm1[k * 64 + j] : Wm1[(64 + k) * 64 + (j - 64)];
    }
}

// ---------------- column-sliced node GEMM (HW-proven round 2) ----------------
// SCALE: write acc*dinv[n]  ("hs" pre-scaled hidden rows)
template <int K, bool RELU, bool BIAS, bool SCALE>
__global__ __launch_bounds__(256) void k_mm_slice(const float* __restrict__ X,
                                                  const float* __restrict__ WT,   // [64][K]
                                                  const float* __restrict__ bias,
                                                  const float* __restrict__ dinv,
                                                  float* __restrict__ Y, int N) {
    int n = blockIdx.x * 256 + threadIdx.x;
    int j0 = blockIdx.y * 16;
    int nc = n < N ? n : N - 1;
    const float* xr = X + (size_t)nc * K;
    const float* wr = WT + (size_t)j0 * K;
    float acc[16];
#pragma unroll
    for (int j = 0; j < 16; ++j) acc[j] = BIAS ? bias[j0 + j] : 0.f;
#pragma unroll 1
    for (int k0 = 0; k0 < K; k0 += 8) {
        float ef[8];
        *(float4*)(ef)     = *(const float4*)(xr + k0);
        *(float4*)(ef + 4) = *(const float4*)(xr + k0 + 4);
        if (RELU) {
#pragma unroll
            for (int kk = 0; kk < 8; ++kk) ef[kk] = fmaxf(ef[kk], 0.f);
        }
#pragma unroll
        for (int j = 0; j < 16; ++j) {
#pragma unroll
            for (int kk = 0; kk < 8; ++kk)
                acc[j] = fmaf(ef[kk], wr[j * K + k0 + kk], acc[j]);
        }
    }
    if (n < N) {
        if (SCALE) {
            float dn = dinv[n];
#pragma unroll
            for (int j = 0; j < 16; ++j) acc[j] *= dn;
        }
        float4* yp = (float4*)(Y + (size_t)n * 64 + j0);
#pragma unroll
        for (int q = 0; q < 4; ++q) yp[q] = *(float4*)(acc + q * 4);
    }
}

// ---------------- fused P+Q GEMM (round-4 proven G8 form): y<4 -> P(+bm1), y>=4 -> Q ----------------
__global__ __launch_bounds__(256) void k_pq_slice(const float* __restrict__ A2,
                                                  const float* __restrict__ WPQ,  // [128][64]
                                                  const float* __restrict__ bm1,
                                                  float* __restrict__ Pb, float* __restrict__ Qb, int N) {
    int n = blockIdx.x * 256 + threadIdx.x;
    int j0g = blockIdx.y * 16;           // 0..127 row into WPQ
    bool isP = j0g < 64;
    int jo = isP ? j0g : j0g - 64;
    float* Y = isP ? Pb : Qb;
    int nc = n < N ? n : N - 1;
    const float* xr = A2 + (size_t)nc * 64;
    const float* wr = WPQ + (size_t)j0g * 64;
    float acc[16];
#pragma unroll
    for (int j = 0; j < 16; ++j) acc[j] = isP ? bm1[jo + j] : 0.f;
#pragma unroll 1
    for (int k0 = 0; k0 < 64; k0 += 8) {
        float ef[8];
        *(float4*)(ef)     = *(const float4*)(xr + k0);
        *(float4*)(ef + 4) = *(const float4*)(xr + k0 + 4);
#pragma unroll
        for (int kk = 0; kk < 8; ++kk) ef[kk] = fmaxf(ef[kk], 0.f);
#pragma unroll
        for (int j = 0; j < 16; ++j)
#pragma unroll
            for (int kk = 0; kk < 8; ++kk)
                acc[j] = fmaf(ef[kk], wr[j * 64 + k0 + kk], acc[j]);
    }
    if (n < N) {
        float4* yp = (float4*)(Y + (size_t)n * 64 + jo);
#pragma unroll
        for (int q = 0; q < 4; ++q) yp[q] = *(float4*)(acc + q * 4);
    }
}

// ---------------- CSR gather over pre-scaled rows: a[d] = bias + dd*(hs[d] + sum_e hs[src_e]) ----------------
// wave = dst node, lane = column. 16-row, then 8-row batches in flight.
template <bool PAIR>
__global__ __launch_bounds__(256) void k_gather(const float* __restrict__ hs, const float* __restrict__ dinv,
                                                const int* __restrict__ row_start, const void* __restrict__ item,
                                                const int* __restrict__ srcArr,
                                                const float* __restrict__ bias,
                                                float* __restrict__ a, int N) {
    int w = threadIdx.x >> 6, lane = threadIdx.x & 63;
    int d = blockIdx.x * 4 + w;
    if (d >= N) return;
    int beg = row_start[d], end = row_start[d + 1];
    float dd = dinv[d];
    float acc = hs[(size_t)d * 64 + lane];   // self-loop term (pre-scaled)
    int k = beg;
    for (; k + 16 <= end; k += 16) {
        int ss[16];
        if (PAIR) {
            const int2* it = (const int2*)item;
#pragma unroll
            for (int u = 0; u < 16; ++u) ss[u] = it[k + u].x;
        } else {
            const int* eid = (const int*)item;
            int ee[16];
#pragma unroll
            for (int u = 0; u < 16; ++u) ee[u] = eid[k + u];
#pragma unroll
            for (int u = 0; u < 16; ++u) ss[u] = srcArr[ee[u]];
        }
        float v[16];
#pragma unroll
        for (int u = 0; u < 16; ++u) v[u] = hs[(size_t)ss[u] * 64 + lane];
#pragma unroll
        for (int u = 0; u < 16; ++u) acc += v[u];
    }
    for (; k + 8 <= end; k += 8) {
        int ss[8];
        if (PAIR) {
            const int2* it = (const int2*)item;
#pragma unroll
            for (int u = 0; u < 8; ++u) ss[u] = it[k + u].x;
        } else {
            const int* eid = (const int*)item;
            int ee[8];
#pragma unroll
            for (int u = 0; u < 8; ++u) ee[u] = eid[k + u];
#pragma unroll
            for (int u = 0; u < 8; ++u) ss[u] = srcArr[ee[u]];
        }
        float v[8];
#pragma unroll
        for (int u = 0; u < 8; ++u) v[u] = hs[(size_t)ss[u] * 64 + lane];
#pragma unroll
        for (int u = 0; u < 8; ++u) acc += v[u];
    }
    for (; k < end; ++k) {
        int s = PAIR ? ((const int2*)item)[k].x : srcArr[((const int*)item)[k]];
        acc += hs[(size_t)s * 64 + lane];
    }
    a[(size_t)d * 64 + lane] = fmaf(acc, dd, bias[lane]);
}

// ---------------- fallback P pass (row-local, in-place over A2) ----------------
__global__ __launch_bounds__(256) void k_p_inplace(float* __restrict__ A2P,
                                                   const float* __restrict__ WPQ,
                                                   const float* __restrict__ bm1, int N) {
    int n = blockIdx.x * 256 + threadIdx.x;
    int nc = n < N ? n : N - 1;
    const float* xr = A2P + (size_t)nc * 64;
    float acc[64];
#pragma unroll
    for (int j = 0; j < 64; ++j) acc[j] = bm1[j];
#pragma unroll 1
    for (int k0 = 0; k0 < 64; k0 += 8) {
        float ef[8];
        *(float4*)(ef)     = *(const float4*)(xr + k0);
        *(float4*)(ef + 4) = *(const float4*)(xr + k0 + 4);
#pragma unroll
        for (int kk = 0; kk < 8; ++kk) ef[kk] = fmaxf(ef[kk], 0.f);
#pragma unroll
        for (int j = 0; j < 64; ++j)
#pragma unroll
            for (int kk = 0; kk < 8; ++kk)
                acc[j] = fmaf(ef[kk], WPQ[j * 64 + k0 + kk], acc[j]);
    }
    if (n < N) {
#pragma unroll
        for (int q = 0; q < 16; ++q)
            *(float4*)(A2P + (size_t)n * 64 + q * 4) = *(float4*)(acc + q * 4);
    }
}

// ---------------- edge epilogue, ORIGINAL order (tier-2 fallback) ----------------
__global__ __launch_bounds__(256) void k_edge_pq(const float* __restrict__ P,
                                                 const float* __restrict__ Q,
                                                 const int* __restrict__ src,
                                                 const int* __restrict__ dst,
                                                 const float* __restrict__ W2T,
                                                 const float* __restrict__ bm2,
                                                 float* __restrict__ out, int E) {
    int e = blockIdx.x * 256 + threadIdx.x;
    int ec = e < E ? e : E - 1;
    int s = src[ec], d = dst[ec];
    const float4* p4 = (const float4*)(P + (size_t)s * 64);
    const float4* q4 = (const float4*)(Q + (size_t)d * 64);
    float z[64];
#pragma unroll
    for (int c = 0; c < 16; ++c) {
        float4 a = p4[c], b = q4[c];
        z[c * 4 + 0] = fmaxf(a.x + b.x, 0.f);
        z[c * 4 + 1] = fmaxf(a.y + b.y, 0.f);
        z[c * 4 + 2] = fmaxf(a.z + b.z, 0.f);
        z[c * 4 + 3] = fmaxf(a.w + b.w, 0.f);
    }
    float o[16];
#pragma unroll
    for (int c = 0; c < 16; ++c) {
        float a = bm2[c];
#pragma unroll
        for (int j = 0; j < 64; ++j) a = fmaf(z[j], W2T[c * 64 + j], a);
        o[c] = a;
    }
    if (e < E) {
        float4* op = (float4*)(out + (size_t)e * 16);
#pragma unroll
        for (int q = 0; q < 4; ++q) op[q] = *(float4*)(o + q * 4);
    }
}

// ---------------- edge epilogue, CSR order, dvec-indexed, fused accumulate (round-4 HW-proven, 66 us) ----------------
// Thread = 1 CSR position. Consecutive threads share d -> Q row L1/L2-broadcast.
template <bool PAIR>
__global__ __launch_bounds__(256) void k_edge_csr(const float* __restrict__ P,
                                                  const float* __restrict__ Q,
                                                  const int* __restrict__ dvec,
                                                  const void* __restrict__ item,
                                                  const int* __restrict__ srcArr,
                                                  const float* __restrict__ W2T,  // [16][64]
                                                  const float* __restrict__ bm2,
                                                  float* __restrict__ out, int E) {
    int i = blockIdx.x * 256 + threadIdx.x;
    int ic = i < E ? i : E - 1;
    int s, e;
    if (PAIR) {
        int2 pe = ((const int2*)item)[ic];
        s = pe.x; e = pe.y;
    } else {
        e = ((const int*)item)[ic];
        s = srcArr[e];
    }
    int d = dvec[ic];
    const float4* p4 = (const float4*)(P + (size_t)s * 64);
    const float4* q4 = (const float4*)(Q + (size_t)d * 64);
    float o[16];
#pragma unroll
    for (int t = 0; t < 16; ++t) o[t] = bm2[t];
#pragma unroll
    for (int cc = 0; cc < 16; ++cc) {
        float4 a = p4[cc], b = q4[cc];
        float z0 = fmaxf(a.x + b.x, 0.f);
        float z1 = fmaxf(a.y + b.y, 0.f);
        float z2 = fmaxf(a.z + b.z, 0.f);
        float z3 = fmaxf(a.w + b.w, 0.f);
#pragma unroll
        for (int t = 0; t < 16; ++t) {
            o[t] = fmaf(z0, W2T[t * 64 + cc * 4 + 0], o[t]);
            o[t] = fmaf(z1, W2T[t * 64 + cc * 4 + 1], o[t]);
            o[t] = fmaf(z2, W2T[t * 64 + cc * 4 + 2], o[t]);
            o[t] = fmaf(z3, W2T[t * 64 + cc * 4 + 3], o[t]);
        }
    }
    if (i < E) {
        float4* op = (float4*)(out + (size_t)e * 16);
#pragma unroll
        for (int q = 0; q < 4; ++q) op[q] = *(float4*)(o + q * 4);
    }
}

extern "C" void kernel_launch(void* const* d_in, const int* in_sizes, int n_in,
                              void* d_out, int out_size, void* d_ws, size_t ws_size,
                              hipStream_t stream) {
    const float* x   = (const float*)d_in[0];
    const int* ei    = (const int*)d_in[1];
    const float* W1  = (const float*)d_in[2];
    const float* b1  = (const float*)d_in[3];
    const float* W2  = (const float*)d_in[4];
    const float* b2  = (const float*)d_in[5];
    const float* Wm1 = (const float*)d_in[6];
    const float* bm1 = (const float*)d_in[7];
    const float* Wm2 = (const float*)d_in[8];
    const float* bm2 = (const float*)d_in[9];
    float* out = (float*)d_out;

    const int H  = in_sizes[3];          // 64
    const int IN = in_sizes[2] / H;      // 128
    const int N  = in_sizes[0] / IN;     // 50000
    const int E  = in_sizes[1] / 2;      // 800000
    const int* src = ei;
    const int* dst = ei + E;

    auto al = [](size_t b) { return (b + 255) & ~(size_t)255; };
    char* ws = (char*)d_ws;

    const size_t wb     = al((size_t)IN * H * 4) + al((size_t)H * H * 4) + al((size_t)2 * H * H * 4) + al((size_t)H * 16 * 4);
    const size_t rowstB = al(((size_t)N + 1) * 4);
    const size_t nodeB  = al((size_t)N * 64 * 4);
    const size_t pairB  = al((size_t)E * 8);
    const size_t eidB   = al((size_t)E * 4);
    const size_t needA  = wb + rowstB + pairB + 3 * nodeB;   // ~45.1 MB
    const size_t needB  = wb + rowstB + eidB  + 3 * nodeB;   // ~41.9 MB

    // tier 0: int2{src,eid} CSR epilogue; tier 1: eid-only (src via ei); tier 2: round-2 fallback
    const int tier = (needA <= ws_size) ? 0 : (needB <= ws_size) ? 1 : 2;

    float *W1T, *W2T, *WPQ, *Wm2T, *bufB, *Qbuf, *Pbuf, *dinv;
    int *deg, *rowst, *cursor, *bsum;
    void* item;
    float* bufA = (float*)d_out;   // hs buffer: dead before the epilogue writes out
    bool slicedP = true;

    size_t off = 0;
    auto alc = [&](size_t b) { void* p = ws + off; off += al(b); return p; };

    if (tier <= 1) {
        W1T  = (float*)alc((size_t)IN * H * 4);
        W2T  = (float*)alc((size_t)H * H * 4);
        WPQ  = (float*)alc((size_t)2 * H * H * 4);
        Wm2T = (float*)alc((size_t)H * 16 * 4);
        rowst = (int*)alc(((size_t)N + 1) * 4);
        item  = alc(tier == 0 ? (size_t)E * 8 : (size_t)E * 4);
        bufB = (float*)alc((size_t)N * 64 * 4);
        Qbuf = (float*)alc((size_t)N * 64 * 4);
        Pbuf = (float*)alc((size_t)N * 64 * 4);
        // deg/dinv/cursor/bsum alias Pbuf: all dead before the P/Q GEMM writes Pbuf
        // (dinv last used by the layer-2 GEMM SCALE, which precedes k_pq_slice)
        char* pz = (char*)Pbuf;
        dinv   = (float*)pz;
        deg    = (int*)(pz + al((size_t)N * 4));
        cursor = (int*)(pz + 2 * al((size_t)N * 4));
        bsum   = (int*)(pz + 3 * al((size_t)N * 4));
    } else {
        // round-2 proven layout: CSR lives in Qbuf (consumed before Q-GEMM writes it)
        dinv = (float*)alc((size_t)N * 4);
        W1T  = (float*)alc((size_t)IN * H * 4);
        W2T  = (float*)alc((size_t)H * H * 4);
        WPQ  = (float*)alc((size_t)2 * H * H * 4);
        Wm2T = (float*)alc((size_t)H * 16 * 4);
        bufB = (float*)alc((size_t)N * 64 * 4);
        Qbuf = (float*)alc((size_t)N * 64 * 4);
        float* PbufSep = (float*)alc((size_t)N * 64 * 4);
        slicedP = (off <= ws_size);
        Pbuf = slicedP ? PbufSep : bufB;
        char* qz = (char*)Qbuf;
        size_t qo = 0;
        deg    = (int*)(qz + qo); qo += al((size_t)N * 4);
        rowst  = (int*)(qz + qo); qo += al(((size_t)N + 1) * 4);
        cursor = (int*)(qz + qo); qo += al((size_t)N * 4);
        bsum   = (int*)(qz + qo); qo += al(1024);
        item   = (void*)(qz + qo);                      // int2 pairs, ~6.4 MB, fits in 12.8
    }

    const int NBn = (N + 255) / 256;   // 196 (<=256 required by k_scan_off)
    const int NBe = (E + 255) / 256;
    const int NG  = (N + 3) / 4;

    // ---- degree + dinv + CSR build ----
    hipMemsetAsync(deg, 0, (size_t)N * sizeof(int), stream);
    k_deg<<<NBe, 256, 0, stream>>>(dst, deg, E);
    k_scan_sum<<<NBn, 256, 0, stream>>>(deg, bsum, dinv, N);
    k_scan_off<<<1, 256, 0, stream>>>(bsum, NBn);
    k_scan_write<<<NBn, 256, 0, stream>>>(deg, bsum, rowst, cursor, N);
    if (tier == 1) k_fill<false><<<NBe, 256, 0, stream>>>(src, dst, cursor, item, E);
    else           k_fill<true ><<<NBe, 256, 0, stream>>>(src, dst, cursor, item, E);

    // ---- merged weight prep ----
    const int prepElems = IN * H + H * H + H * 16 + 2 * H * H;
    k_prep<<<(prepElems + 255) / 256, 256, 0, stream>>>(W1, W2, Wm2, Wm1, W1T, W2T, Wm2T, WPQ, IN, H);

    const dim3 G4(NBn, 4);
    const dim3 G8(NBn, 8);

    // layer 1: hs1 = (x@W1)*dinv -> bufA ; a1 = b1 + dd*(hs1[d] + sum hs1[s]) -> bufB
    k_mm_slice<128, false, false, true><<<G4, 256, 0, stream>>>(x, W1T, nullptr, dinv, bufA, N);
    if (tier == 1) k_gather<false><<<NG, 256, 0, stream>>>(bufA, dinv, rowst, item, src, b1, bufB, N);
    else           k_gather<true ><<<NG, 256, 0, stream>>>(bufA, dinv, rowst, item, src, b1, bufB, N);

    // layer 2: hs2 = (relu(a1)@W2)*dinv -> bufA ; a2 -> bufB
    k_mm_slice<64, true, false, true><<<G4, 256, 0, stream>>>(bufB, W2T, nullptr, dinv, bufA, N);
    if (tier == 1) k_gather<false><<<NG, 256, 0, stream>>>(bufA, dinv, rowst, item, src, b2, bufB, N);
    else           k_gather<true ><<<NG, 256, 0, stream>>>(bufA, dinv, rowst, item, src, b2, bufB, N);

    // node-side MLP halves
    if (tier <= 1) {
        // fused P+Q dispatch (round-4 proven G8 form); dinv dead from here
        k_pq_slice<<<G8, 256, 0, stream>>>(bufB, WPQ, bm1, Pbuf, Qbuf, N);
        // dvec into bufB (a2 dead after k_pq_slice)
        int* dvec = (int*)bufB;
        k_dvec<<<NG, 256, 0, stream>>>(rowst, dvec, N);
        if (tier == 0) k_edge_csr<true ><<<NBe, 256, 0, stream>>>(Pbuf, Qbuf, dvec, item, src, Wm2T, bm2, out, E);
        else           k_edge_csr<false><<<NBe, 256, 0, stream>>>(Pbuf, Qbuf, dvec, item, src, Wm2T, bm2, out, E);
    } else {
        k_mm_slice<64, true, false, false><<<G4, 256, 0, stream>>>(bufB, WPQ + 64 * 64, nullptr, nullptr, Qbuf, N);
        if (slicedP) k_mm_slice<64, true, true, false><<<G4, 256, 0, stream>>>(bufB, WPQ, bm1, nullptr, Pbuf, N);
        else         k_p_inplace<<<NBn, 256, 0, stream>>>(bufB, WPQ, bm1, N);
        k_edge_pq<<<NBe, 256, 0, stream>>>(Pbuf, Qbuf, src, dst, Wm2T, bm2, out, E);
    }
}